// Round 2
// baseline (226.855 us; speedup 1.0000x reference)
//
#include <hip/hip_runtime.h>
#include <hip/hip_cooperative_groups.h>

namespace cg = cooperative_groups;

constexpr int kB  = 16;
constexpr int kM  = 512;
constexpr int kS  = 32;
constexpr int kE  = 128;
constexpr int kV  = 32000;
constexpr int kVN = kV - 1;   // nil (zero) row index

// -------------------------------------------------------------------------
// Kernel 1: story embeddings. 2 rows per 256-thread block, grid = 4096.
// Per row: 8 groups of 32 lanes; group = (row-in-pair, s-phase). Each lane
// gathers float4 (4 e-elems) for 8 s values -> 16 independent loads in
// flight. Partials reduced through LDS.
// enc[s][e] = 1 + (e-63)(s-15)/1024  (exact f32 match of numpy formula)
// -------------------------------------------------------------------------
__global__ __launch_bounds__(256) void embed_stories_kernel(
    const int*   __restrict__ stories,   // [B,M,S]
    const float* __restrict__ st_bias,   // [VN,E]
    const float* __restrict__ out_bias,  // [VN,E]
    const float* __restrict__ mem_bias,  // [M,E]
    float*       __restrict__ memory,    // [B,M,E]
    float*       __restrict__ output)    // [B,M,E]
{
    __shared__ int sidx[2][kS];
    __shared__ __align__(16) float pm[8][kE];
    __shared__ __align__(16) float po[8][kE];

    const int t    = threadIdx.x;
    const int row0 = blockIdx.x * 2;           // (b*M+m) of first row
    if (t < 64) sidx[t >> 5][t & 31] = stories[row0 * kS + t];
    __syncthreads();

    const int g    = t >> 5;       // 0..7
    const int lane = t & 31;
    const int p    = g >> 2;       // which row of the pair
    const int ph   = g & 3;        // s-phase (8 s values each)
    const int e0   = lane * 4;
    const float ef0 = (float)(e0 - 63), ef1 = (float)(e0 - 62);
    const float ef2 = (float)(e0 - 61), ef3 = (float)(e0 - 60);

    float4 am = {0.f, 0.f, 0.f, 0.f};
    float4 ao = {0.f, 0.f, 0.f, 0.f};
    #pragma unroll
    for (int j = 0; j < 8; ++j) {
        const int s   = ph * 8 + j;
        const int idx = sidx[p][s];
        const float sf = (float)(s - 15) * (1.0f / 1024.0f);
        if (idx < kVN) {
            const float4 vm = *(const float4*)(st_bias  + (size_t)idx * kE + e0);
            const float4 vo = *(const float4*)(out_bias + (size_t)idx * kE + e0);
            const float c0 = fmaf(ef0, sf, 1.0f), c1 = fmaf(ef1, sf, 1.0f);
            const float c2 = fmaf(ef2, sf, 1.0f), c3 = fmaf(ef3, sf, 1.0f);
            am.x = fmaf(vm.x, c0, am.x); am.y = fmaf(vm.y, c1, am.y);
            am.z = fmaf(vm.z, c2, am.z); am.w = fmaf(vm.w, c3, am.w);
            ao.x = fmaf(vo.x, c0, ao.x); ao.y = fmaf(vo.y, c1, ao.y);
            ao.z = fmaf(vo.z, c2, ao.z); ao.w = fmaf(vo.w, c3, ao.w);
        }
    }
    *(float4*)&pm[g][e0] = am;
    *(float4*)&po[g][e0] = ao;
    __syncthreads();

    const int pr = t >> 7;         // row of pair
    const int e  = t & 127;
    const int row = row0 + pr;
    const int m   = row & (kM - 1);
    const float sm = pm[pr * 4 + 0][e] + pm[pr * 4 + 1][e] +
                     pm[pr * 4 + 2][e] + pm[pr * 4 + 3][e];
    const float so = po[pr * 4 + 0][e] + po[pr * 4 + 1][e] +
                     po[pr * 4 + 2][e] + po[pr * 4 + 3][e];
    memory[(size_t)row * kE + e] = sm + mem_bias[m * kE + e];
    output[(size_t)row * kE + e] = so;
}

// -------------------------------------------------------------------------
// Kernel 2 (cooperative, 256 blocks x 256 threads): q-embed + 3 hops + final
// matmul. b = bid%16 (keeps same-b blocks on one XCD for L2 locality),
// rep = bid>>4. Hops are fully block-redundant (no grid sync inside the
// loop); one grid.sync() to exchange x (8 KB), then v-split final matmul.
// -------------------------------------------------------------------------
__global__ __launch_bounds__(256) void hops_final_kernel(
    const int*   __restrict__ queries,  // [B,S]
    const float* __restrict__ q_bias,   // [VN,E]
    const float* __restrict__ memory,   // [B,M,E]
    const float* __restrict__ output,   // [B,M,E]
    const float* __restrict__ w_int,    // [E,E]
    const float* __restrict__ w_out,    // [E,E]
    const float* __restrict__ w_final,  // [E,V]
    float*       __restrict__ xg,       // [B,E] scratch
    float*       __restrict__ out)      // [B,V]
{
    __shared__ int qidx[kS];
    __shared__ __align__(16) float pq[8][kE];
    __shared__ __align__(16) float q_s[kE];
    __shared__ float s_s[kM];            // probs
    __shared__ __align__(16) float part2[2][kE];
    __shared__ float xb[kE];
    __shared__ float redA[4], redB[4];
    __shared__ __align__(16) float xs[kB][kE];

    cg::grid_group grid = cg::this_grid();
    const int bid = blockIdx.x;
    const int b   = bid & 15;
    const int rep = bid >> 4;
    const int t   = threadIdx.x;

    if (t < kS) qidx[t] = queries[b * kS + t];
    __syncthreads();

    // ---- q embedding: 8 s-phases x 32 lanes (float4) ----
    {
        const int g = t >> 5, lane = t & 31, e0 = lane * 4;
        const float ef0 = (float)(e0 - 63), ef1 = (float)(e0 - 62);
        const float ef2 = (float)(e0 - 61), ef3 = (float)(e0 - 60);
        float4 a = {0.f, 0.f, 0.f, 0.f};
        #pragma unroll
        for (int j = 0; j < 4; ++j) {
            const int s   = g * 4 + j;
            const int idx = qidx[s];
            const float sf = (float)(s - 15) * (1.0f / 1024.0f);
            if (idx < kVN) {
                const float4 v = *(const float4*)(q_bias + (size_t)idx * kE + e0);
                a.x = fmaf(v.x, fmaf(ef0, sf, 1.0f), a.x);
                a.y = fmaf(v.y, fmaf(ef1, sf, 1.0f), a.y);
                a.z = fmaf(v.z, fmaf(ef2, sf, 1.0f), a.z);
                a.w = fmaf(v.w, fmaf(ef3, sf, 1.0f), a.w);
            }
        }
        *(float4*)&pq[g][e0] = a;
    }
    __syncthreads();
    if (t < kE) {
        float s = 0.f;
        #pragma unroll
        for (int g = 0; g < 8; ++g) s += pq[g][t];
        q_s[t] = s;
    }
    __syncthreads();

    const float* memb = memory + (size_t)b * kM * kE;
    const float* outb = output + (size_t)b * kM * kE;
    const int e    = t & 127;
    const int half = t >> 7;

    for (int hop = 0; hop < 3; ++hop) {
        // ---- scores: thread t owns rows m=t and m=t+256 ----
        float sv0, sv1;
        {
            const float4* q4 = (const float4*)q_s;
            const float4* r0 = (const float4*)(memb + (size_t)t * kE);
            const float4* r1 = (const float4*)(memb + (size_t)(t + 256) * kE);
            float a0 = 0.f, a1 = 0.f, b0 = 0.f, b1 = 0.f;
            #pragma unroll 4
            for (int i = 0; i < 32; i += 2) {
                const float4 x0 = r0[i], y0 = r0[i + 1];
                const float4 x1 = r1[i], y1 = r1[i + 1];
                const float4 qa = q4[i], qb = q4[i + 1];
                a0 = fmaf(x0.x, qa.x, a0); a0 = fmaf(x0.y, qa.y, a0);
                a0 = fmaf(x0.z, qa.z, a0); a0 = fmaf(x0.w, qa.w, a0);
                b0 = fmaf(y0.x, qb.x, b0); b0 = fmaf(y0.y, qb.y, b0);
                b0 = fmaf(y0.z, qb.z, b0); b0 = fmaf(y0.w, qb.w, b0);
                a1 = fmaf(x1.x, qa.x, a1); a1 = fmaf(x1.y, qa.y, a1);
                a1 = fmaf(x1.z, qa.z, a1); a1 = fmaf(x1.w, qa.w, a1);
                b1 = fmaf(y1.x, qb.x, b1); b1 = fmaf(y1.y, qb.y, b1);
                b1 = fmaf(y1.z, qb.z, b1); b1 = fmaf(y1.w, qb.w, b1);
            }
            sv0 = a0 + b0; sv1 = a1 + b1;
        }
        // ---- softmax over 512 (regs + shfl + LDS) ----
        float ml = fmaxf(sv0, sv1);
        #pragma unroll
        for (int off = 32; off; off >>= 1) ml = fmaxf(ml, __shfl_down(ml, off));
        if ((t & 63) == 0) redA[t >> 6] = ml;
        __syncthreads();
        const float mx = fmaxf(fmaxf(redA[0], redA[1]), fmaxf(redA[2], redA[3]));
        const float ex0 = __expf(sv0 - mx), ex1 = __expf(sv1 - mx);
        float sl = ex0 + ex1;
        #pragma unroll
        for (int off = 32; off; off >>= 1) sl += __shfl_down(sl, off);
        if ((t & 63) == 0) redB[t >> 6] = sl;
        __syncthreads();
        const float inv = 1.0f / (redB[0] + redB[1] + redB[2] + redB[3]);
        s_s[t]       = ex0 * inv;
        s_s[t + 256] = ex1 * inv;
        __syncthreads();

        // ---- layer_out[e] = sum_m p[m]*output[b,m,e], halves over m ----
        {
            const float* ob = outb + (size_t)half * 256 * kE + e;
            const int mb = half * 256;
            float a0 = 0.f, a1 = 0.f, a2 = 0.f, a3 = 0.f;
            #pragma unroll 4
            for (int m = 0; m < 256; m += 4) {
                a0 = fmaf(s_s[mb + m + 0], ob[(size_t)(m + 0) * kE], a0);
                a1 = fmaf(s_s[mb + m + 1], ob[(size_t)(m + 1) * kE], a1);
                a2 = fmaf(s_s[mb + m + 2], ob[(size_t)(m + 2) * kE], a2);
                a3 = fmaf(s_s[mb + m + 3], ob[(size_t)(m + 3) * kE], a3);
            }
            part2[half][e] = (a0 + a1) + (a2 + a3);
        }
        __syncthreads();
        if (t < kE) xb[t] = q_s[t] + part2[0][t] + part2[1][t];
        __syncthreads();

        // ---- new_q[e'] = sum_k xb[k] * w[k,e'] ----
        {
            const float* w = (hop == 2) ? w_out : w_int;
            float c0 = 0.f, c1 = 0.f;
            #pragma unroll 8
            for (int k = 0; k < 64; k += 2) {
                const int kk = half * 64 + k;
                c0 = fmaf(xb[kk],     w[(kk)     * kE + e], c0);
                c1 = fmaf(xb[kk + 1], w[(kk + 1) * kE + e], c1);
            }
            part2[half][e] = c0 + c1;
        }
        __syncthreads();
        if (t < kE) q_s[t] = part2[0][t] + part2[1][t];
        __syncthreads();
    }

    // ---- publish x[b] = relu(q), exchange across blocks ----
    if (rep == 0 && t < kE) xg[b * kE + t] = fmaxf(q_s[t], 0.f);
    grid.sync();

    // ---- final matmul: block owns 125 v-columns ----
    for (int i = t; i < kB * kE; i += 256) xs[i >> 7][i & 127] = xg[i];
    __syncthreads();
    if (t < 125) {
        const int v = bid * 125 + t;
        float acc[kB];
        #pragma unroll
        for (int b2 = 0; b2 < kB; ++b2) acc[b2] = 0.f;
        for (int e2 = 0; e2 < kE; ++e2) {
            const float wv = w_final[(size_t)e2 * kV + v];
            #pragma unroll
            for (int b2 = 0; b2 < kB; ++b2)
                acc[b2] = fmaf(xs[b2][e2], wv, acc[b2]);
        }
        #pragma unroll
        for (int b2 = 0; b2 < kB; ++b2) out[(size_t)b2 * kV + v] = acc[b2];
    }
}

// -------------------------------------------------------------------------
extern "C" void kernel_launch(void* const* d_in, const int* in_sizes, int n_in,
                              void* d_out, int out_size, void* d_ws, size_t ws_size,
                              hipStream_t stream)
{
    const int*   queries  = (const int*)  d_in[0];
    const int*   stories  = (const int*)  d_in[1];
    const float* q_bias   = (const float*)d_in[2];
    const float* st_bias  = (const float*)d_in[3];
    const float* mem_bias = (const float*)d_in[4];
    const float* out_bias = (const float*)d_in[5];
    const float* w_int    = (const float*)d_in[6];
    const float* w_out    = (const float*)d_in[7];
    const float* w_final  = (const float*)d_in[8];
    float* out = (float*)d_out;

    // ws: memory[B*M*E] | output[B*M*E] | xg[B*E]
    float* memory = (float*)d_ws;
    float* output = memory + (size_t)kB * kM * kE;
    float* xg     = output + (size_t)kB * kM * kE;

    embed_stories_kernel<<<dim3((kB * kM) / 2), dim3(256), 0, stream>>>(
        stories, st_bias, out_bias, mem_bias, memory, output);

    void* args[] = {
        (void*)&queries, (void*)&q_bias, (void*)&memory, (void*)&output,
        (void*)&w_int, (void*)&w_out, (void*)&w_final, (void*)&xg, (void*)&out
    };
    hipLaunchCooperativeKernel((const void*)hops_final_kernel,
                               dim3(256), dim3(256), args, 0, stream);
}